// Round 2
// baseline (72.315 us; speedup 1.0000x reference)
//
#include <hip/hip_runtime.h>
#include <hip/hip_bf16.h>

// Fast exp2 -> single v_exp_f32
#if defined(__has_builtin)
#if __has_builtin(__builtin_amdgcn_exp2f)
#define FAST_EXP2(x) __builtin_amdgcn_exp2f(x)
#endif
#endif
#ifndef FAST_EXP2
#define FAST_EXP2(x) exp2f(x)
#endif

#define N_TRAIN 8192
#define BSZ 4096
#define NOUT (BSZ * 3)   // 12288
#define BLK 256
#define RPT 4            // batch points per thread
#define BPB (BLK * RPT)  // 1024 batch points per block
#define NBB (BSZ / BPB)  // 4 b-blocks

// ---------------------------------------------------------------------------
// prep: per train point n, z = W @ train_X[n]:
//   TB[n] = { c*z0^2, c*z1^2, c*z2^2, Y[n],  -2c*z0, -2c*z1, -2c*z2, 0 }
// per batch point b: XW[b] = (xw0, xw1, xw2, 0), xw = W @ x[b].
// c = -log2(e)/(2h^2). The dropped exp2(c*xw^2) factor cancels in num/den.
// ---------------------------------------------------------------------------
__global__ __launch_bounds__(BLK) void prep_k(
    const float4* __restrict__ x4,    // [4096]
    const float4* __restrict__ tX4,   // [8192]
    const float*  __restrict__ Y,     // [8192]
    const float*  __restrict__ W,     // [3][4]
    const float*  __restrict__ hptr,  // [1]
    float4* __restrict__ TB,          // [8192][2]
    float4* __restrict__ XW)          // [4096]
{
    int idx = blockIdx.x * BLK + threadIdx.x;
    float h = hptr[0];
    float c = -0.72134752044448170368f / (h * h);  // -log2(e)/2 / h^2

    const float4* Wv = (const float4*)W;
    float4 w0 = Wv[0], w1 = Wv[1], w2 = Wv[2];

    if (idx < N_TRAIN) {
        float4 t = tX4[idx];
        float z0 = t.x * w0.x + t.y * w0.y + t.z * w0.z + t.w * w0.w;
        float z1 = t.x * w1.x + t.y * w1.y + t.z * w1.z + t.w * w1.w;
        float z2 = t.x * w2.x + t.y * w2.y + t.z * w2.z + t.w * w2.w;
        TB[2 * idx]     = make_float4(c * z0 * z0, c * z1 * z1, c * z2 * z2, Y[idx]);
        TB[2 * idx + 1] = make_float4(-2.f * c * z0, -2.f * c * z1, -2.f * c * z2, 0.f);
    } else {
        int b = idx - N_TRAIN;  // < 4096
        float4 t = x4[b];
        float x0 = t.x * w0.x + t.y * w0.y + t.z * w0.z + t.w * w0.w;
        float x1 = t.x * w1.x + t.y * w1.y + t.z * w1.z + t.w * w1.w;
        float x2 = t.x * w2.x + t.y * w2.y + t.z * w2.z + t.w * w2.w;
        XW[b] = make_float4(x0, x1, x2, 0.f);
    }
}

// ---------------------------------------------------------------------------
// main: block = 256 threads; each thread owns RPT=4 batch points (strided by
// 256 within the block's 1024-b slice). Per train point n: ONE wave-uniform
// 32B load (scalar-cache path; address depends only on blockIdx/loop index),
// then 12 fma + 12 exp2 + 12 add + 12 fma on the vector pipes. No LDS.
// Partials layout: [seg][d][4096] for fully-coalesced stores.
// ---------------------------------------------------------------------------
__global__ __launch_bounds__(BLK) void kde_k(
    const float4* __restrict__ TB,   // [8192][2]
    const float4* __restrict__ XW,   // [4096]
    float* __restrict__ NP,          // [ns][3][4096]
    float* __restrict__ DP,          // [ns][3][4096]
    int nb)                          // train points per segment
{
    int tid  = threadIdx.x;
    int bblk = blockIdx.x & (NBB - 1);   // 4 b-blocks
    int seg  = blockIdx.x / NBB;
    int n0   = seg * nb;
    int b0   = bblk * BPB + tid;

    float4 xw[RPT];
    #pragma unroll
    for (int r = 0; r < RPT; ++r) xw[r] = XW[b0 + r * BLK];

    float num[RPT][3], den[RPT][3];
    #pragma unroll
    for (int r = 0; r < RPT; ++r)
        #pragma unroll
        for (int d = 0; d < 3; ++d) { num[r][d] = 0.f; den[r][d] = 0.f; }

    #pragma unroll 2
    for (int t = 0; t < nb; ++t) {
        int n = n0 + t;                 // uniform (blockIdx/loop only)
        float4 a  = TB[2 * n];          // A0 A1 A2 Y
        float4 bb = TB[2 * n + 1];      // B0 B1 B2 -

        #pragma unroll
        for (int r = 0; r < RPT; ++r) {
            float e0 = FAST_EXP2(fmaf(bb.x, xw[r].x, a.x));
            float e1 = FAST_EXP2(fmaf(bb.y, xw[r].y, a.y));
            float e2 = FAST_EXP2(fmaf(bb.z, xw[r].z, a.z));
            den[r][0] += e0;
            den[r][1] += e1;
            den[r][2] += e2;
            num[r][0] = fmaf(e0, a.w, num[r][0]);
            num[r][1] = fmaf(e1, a.w, num[r][1]);
            num[r][2] = fmaf(e2, a.w, num[r][2]);
        }
    }

    size_t sb = (size_t)seg * NOUT;
    #pragma unroll
    for (int r = 0; r < RPT; ++r) {
        int b = b0 + r * BLK;
        #pragma unroll
        for (int d = 0; d < 3; ++d) {
            NP[sb + (size_t)d * BSZ + b] = num[r][d];
            DP[sb + (size_t)d * BSZ + b] = den[r][d];
        }
    }
}

// ---------------------------------------------------------------------------
// reduce: one thread per (d,b) element in partial layout, sum ns partials,
// divide, store to out[b*3+d].
// ---------------------------------------------------------------------------
__global__ __launch_bounds__(BLK) void reduce_k(
    const float* __restrict__ NP,
    const float* __restrict__ DP,
    float* __restrict__ out,
    int ns)
{
    int t = blockIdx.x * BLK + threadIdx.x;  // < 12288, t = d*4096 + b
    float n = 0.f, d = 0.f;
    for (int s = 0; s < ns; ++s) {
        n += NP[(size_t)s * NOUT + t];
        d += DP[(size_t)s * NOUT + t];
    }
    int b  = t & (BSZ - 1);
    int dd = t >> 12;
    out[b * 3 + dd] = n / d;
}

extern "C" void kernel_launch(void* const* d_in, const int* in_sizes, int n_in,
                              void* d_out, int out_size, void* d_ws, size_t ws_size,
                              hipStream_t stream) {
    const float* x   = (const float*)d_in[0];  // [4096,4]
    const float* tX  = (const float*)d_in[1];  // [8192,4]
    const float* Y   = (const float*)d_in[2];  // [8192]
    const float* W   = (const float*)d_in[3];  // [3,4]
    const float* h   = (const float*)d_in[4];  // [1]
    float* out = (float*)d_out;                // [4096,3]

    // ws layout: TB [8192][2] float4 (256 KB) | XW [4096] float4 (64 KB)
    //            NP [ns][12288] f32 | DP [ns][12288] f32
    float4* TB = (float4*)d_ws;
    float4* XW = TB + 2 * N_TRAIN;
    float*  NP = (float*)(XW + BSZ);

    size_t fixed_bytes = (size_t)(2 * N_TRAIN + BSZ) * sizeof(float4);
    int ns = 128;  // n-segments -> grid = 4*ns = 512 blocks (2/CU, 8 waves/CU)
    while (ns > 1 &&
           fixed_bytes + (size_t)ns * NOUT * 2 * sizeof(float) > ws_size) {
        ns >>= 1;
    }
    float* DP = NP + (size_t)ns * NOUT;
    int nb = N_TRAIN / ns;

    prep_k<<<(N_TRAIN + BSZ) / BLK, BLK, 0, stream>>>(
        (const float4*)x, (const float4*)tX, Y, W, h, TB, XW);

    kde_k<<<NBB * ns, BLK, 0, stream>>>(TB, XW, NP, DP, nb);

    reduce_k<<<NOUT / BLK, BLK, 0, stream>>>(NP, DP, out, ns);
}

// Round 3
// 42.236 us; speedup vs baseline: 1.7122x; 1.7122x over previous
//
#include <hip/hip_runtime.h>
#include <hip/hip_bf16.h>

// Fast exp2 -> single v_exp_f32
#if defined(__has_builtin)
#if __has_builtin(__builtin_amdgcn_exp2f)
#define FAST_EXP2(x) __builtin_amdgcn_exp2f(x)
#endif
#endif
#ifndef FAST_EXP2
#define FAST_EXP2(x) exp2f(x)
#endif

#define N_TRAIN 8192
#define BSZ 4096
#define NOUT (BSZ * 3)   // 12288
#define BLK 256
#define NS  32           // n-segments (compile-time!)
#define NBB 16           // b-blocks of 256
#define NB  (N_TRAIN / NS)  // 256 train points per segment

// ---------------------------------------------------------------------------
// prep: per train point n, z = W @ train_X[n]:
//   TB[2n]   = { c*z0^2, c*z1^2, c*z2^2, Y[n] }
//   TB[2n+1] = { -2c*z0, -2c*z1, -2c*z2, 0 }
// per batch point b: XW[b] = (xw0, xw1, xw2, 0), xw = W @ x[b].
// c = -log2(e)/(2h^2). The dropped exp2(c*xw^2) factor cancels in num/den.
// ---------------------------------------------------------------------------
__global__ __launch_bounds__(BLK) void prep_k(
    const float4* __restrict__ x4,    // [4096]
    const float4* __restrict__ tX4,   // [8192]
    const float*  __restrict__ Y,     // [8192]
    const float*  __restrict__ W,     // [3][4]
    const float*  __restrict__ hptr,  // [1]
    float4* __restrict__ TB,          // [8192][2]
    float4* __restrict__ XW)          // [4096]
{
    int idx = blockIdx.x * BLK + threadIdx.x;
    float h = hptr[0];
    float c = -0.72134752044448170368f / (h * h);  // -log2(e)/2 / h^2

    const float4* Wv = (const float4*)W;
    float4 w0 = Wv[0], w1 = Wv[1], w2 = Wv[2];

    if (idx < N_TRAIN) {
        float4 t = tX4[idx];
        float z0 = t.x * w0.x + t.y * w0.y + t.z * w0.z + t.w * w0.w;
        float z1 = t.x * w1.x + t.y * w1.y + t.z * w1.z + t.w * w1.w;
        float z2 = t.x * w2.x + t.y * w2.y + t.z * w2.z + t.w * w2.w;
        TB[2 * idx]     = make_float4(c * z0 * z0, c * z1 * z1, c * z2 * z2, Y[idx]);
        TB[2 * idx + 1] = make_float4(-2.f * c * z0, -2.f * c * z1, -2.f * c * z2, 0.f);
    } else {
        int b = idx - N_TRAIN;  // < 4096
        float4 t = x4[b];
        float x0 = t.x * w0.x + t.y * w0.y + t.z * w0.z + t.w * w0.w;
        float x1 = t.x * w1.x + t.y * w1.y + t.z * w1.z + t.w * w1.w;
        float x2 = t.x * w2.x + t.y * w2.y + t.z * w2.z + t.w * w2.w;
        XW[b] = make_float4(x0, x1, x2, 0.f);
    }
}

// ---------------------------------------------------------------------------
// main: 512 blocks = 16 b-blocks x 32 segments; thread owns one batch point.
// Per train point n: two wave-uniform 16B loads (scalar-cache / L1-broadcast
// path, address depends only on blockIdx + loop var), then per dim:
// 1 fma (arg) + 1 exp2 + 1 add (den) + 1 fma (num). No LDS.
// Partials layout [seg][d][4096] -> fully coalesced stores and reduce loads.
// ---------------------------------------------------------------------------
__global__ __launch_bounds__(BLK) void kde_k(
    const float4* __restrict__ TB,   // [8192][2]
    const float4* __restrict__ XW,   // [4096]
    float* __restrict__ NP,          // [NS][3][4096]
    float* __restrict__ DP)          // [NS][3][4096]
{
    int tid  = threadIdx.x;
    int bblk = blockIdx.x & (NBB - 1);   // 16 b-blocks
    int seg  = blockIdx.x / NBB;         // 32 segments
    int n0   = seg * NB;
    int b    = (bblk << 8) + tid;

    float4 xw = XW[b];
    float num0 = 0.f, num1 = 0.f, num2 = 0.f;
    float den0 = 0.f, den1 = 0.f, den2 = 0.f;

    #pragma unroll 4
    for (int t = 0; t < NB; ++t) {
        int n = n0 + t;                 // wave-uniform
        float4 a  = TB[2 * n];          // A0 A1 A2 Y
        float4 bb = TB[2 * n + 1];      // B0 B1 B2 -

        float e0 = FAST_EXP2(fmaf(bb.x, xw.x, a.x));
        float e1 = FAST_EXP2(fmaf(bb.y, xw.y, a.y));
        float e2 = FAST_EXP2(fmaf(bb.z, xw.z, a.z));
        den0 += e0;
        den1 += e1;
        den2 += e2;
        num0 = fmaf(e0, a.w, num0);
        num1 = fmaf(e1, a.w, num1);
        num2 = fmaf(e2, a.w, num2);
    }

    size_t sb = (size_t)seg * NOUT + b;
    NP[sb]           = num0;
    NP[sb + BSZ]     = num1;
    NP[sb + 2 * BSZ] = num2;
    DP[sb]           = den0;
    DP[sb + BSZ]     = den1;
    DP[sb + 2 * BSZ] = den2;
}

// ---------------------------------------------------------------------------
// reduce: one thread per (d,b) element; NS is compile-time -> fully unrolled,
// 2*NS independent coalesced loads in flight per thread.
// ---------------------------------------------------------------------------
__global__ __launch_bounds__(BLK) void reduce_k(
    const float* __restrict__ NP,
    const float* __restrict__ DP,
    float* __restrict__ out)
{
    int t = blockIdx.x * BLK + threadIdx.x;  // < 12288, t = d*4096 + b
    float n = 0.f, d = 0.f;
    #pragma unroll
    for (int s = 0; s < NS; ++s) {
        n += NP[(size_t)s * NOUT + t];
        d += DP[(size_t)s * NOUT + t];
    }
    int b  = t & (BSZ - 1);
    int dd = t >> 12;
    out[b * 3 + dd] = n / d;
}

extern "C" void kernel_launch(void* const* d_in, const int* in_sizes, int n_in,
                              void* d_out, int out_size, void* d_ws, size_t ws_size,
                              hipStream_t stream) {
    const float* x   = (const float*)d_in[0];  // [4096,4]
    const float* tX  = (const float*)d_in[1];  // [8192,4]
    const float* Y   = (const float*)d_in[2];  // [8192]
    const float* W   = (const float*)d_in[3];  // [3,4]
    const float* h   = (const float*)d_in[4];  // [1]
    float* out = (float*)d_out;                // [4096,3]

    // ws layout: TB [8192][2] float4 (256 KB) | XW [4096] float4 (64 KB)
    //            NP [NS][12288] f32 (1.57 MB) | DP [NS][12288] f32 (1.57 MB)
    float4* TB = (float4*)d_ws;
    float4* XW = TB + 2 * N_TRAIN;
    float*  NP = (float*)(XW + BSZ);
    float*  DP = NP + (size_t)NS * NOUT;

    prep_k<<<(N_TRAIN + BSZ) / BLK, BLK, 0, stream>>>(
        (const float4*)x, (const float4*)tX, Y, W, h, TB, XW);

    kde_k<<<NBB * NS, BLK, 0, stream>>>(TB, XW, NP, DP);

    reduce_k<<<NOUT / BLK, BLK, 0, stream>>>(NP, DP, out);
}